// Round 2
// baseline (2795.086 us; speedup 1.0000x reference)
//
#include <hip/hip_runtime.h>
#include <math.h>

#define NB   16384
#define NF   39
#define ND   16
#define NDH  32
#define NVOC 10000
#define PIT  33   // fp32 pitch: odd -> conflict-free column access across lanes

__device__ __forceinline__ float wmaxf(float v){
#pragma unroll
    for (int off = 32; off; off >>= 1) v = fmaxf(v, __shfl_xor(v, off, 64));
    return v;
}
__device__ __forceinline__ float wsumf(float v){
#pragma unroll
    for (int off = 32; off; off >>= 1) v += __shfl_xor(v, off, 64);
    return v;
}

// One wave (64 lanes) processes one batch row's attention layer.
// m = lane>>5 selects {K,V} in phase 1 and {Q,R} in phase 2; j = lane&31 is the output column.
template<int DIN>
__device__ __forceinline__ void attn_layer(
    const float* Ein, float* Eout, float* sK, float* sV, float* sQ, float* sAtt,
    const float* __restrict__ wq, const float* __restrict__ wk,
    const float* __restrict__ wv, const float* __restrict__ wr, int lane)
{
    const int m = lane >> 5;
    const int j = lane & 31;
    // ---- phase 1: K = Ein@wk, V = Ein@wv (weight column held in registers) ----
    {
        const float* w = m ? wv : wk;
        float wc[DIN];
#pragma unroll
        for (int d = 0; d < DIN; ++d) wc[d] = w[d*NDH + j];
        float* dst = m ? sV : sK;
        for (int f = 0; f < NF; ++f){
            float acc = 0.f;
#pragma unroll
            for (int d = 0; d < DIN; ++d) acc += Ein[f*PIT + d] * wc[d];  // LDS broadcast read
            dst[f*PIT + j] = acc;
        }
    }
    // ---- phase 2: per output position f: q/r, scores, softmax, att@V + r, relu ----
    {
        const float* w = m ? wr : wq;
        float wc[DIN];
#pragma unroll
        for (int d = 0; d < DIN; ++d) wc[d] = w[d*NDH + j];
        __syncthreads();  // K,V visible
        for (int f = 0; f < NF; ++f){
            float qr = 0.f;  // q_j (m==0) or r_j (m==1)
#pragma unroll
            for (int d = 0; d < DIN; ++d) qr += Ein[f*PIT + d] * wc[d];
            if (m == 0) sQ[j] = qr;
            __syncthreads();
            // scores: lane g computes s_g = q . K[g]
            float sg;
            if (lane < NF){
                sg = 0.f;
#pragma unroll
                for (int jj = 0; jj < NDH; ++jj) sg += sQ[jj] * sK[lane*PIT + jj];
            } else sg = -INFINITY;
            float mx = wmaxf(sg);
            float p  = (lane < NF) ? __expf(sg - mx) : 0.f;
            float su = wsumf(p);
            if (lane < NF) sAtt[lane] = p * (1.f / su);
            __syncthreads();
            // out_f[j] = sum_g att_g * V[g][j] ; halves split even/odd g, combine via xor-32
            float o = 0.f;
            for (int g = m; g < NF; g += 2) o += sAtt[g] * sV[g*PIT + j];
            o += __shfl_xor(o, 32, 64);
            if (m == 1) Eout[f*PIT + j] = fmaxf(o + qr, 0.f);  // qr = r_j in high half
            __syncthreads();
        }
    }
}

__global__ void __launch_bounds__(64) autoint_fused(
    const int* __restrict__ x, const float* __restrict__ emb,
    const float* __restrict__ wq0, const float* __restrict__ wk0, const float* __restrict__ wv0, const float* __restrict__ wr0,
    const float* __restrict__ wq1, const float* __restrict__ wk1, const float* __restrict__ wv1, const float* __restrict__ wr1,
    const float* __restrict__ wq2, const float* __restrict__ wk2, const float* __restrict__ wv2, const float* __restrict__ wr2,
    const float* __restrict__ w1, const float* __restrict__ b1,
    const float* __restrict__ w2, const float* __restrict__ b2,
    const float* __restrict__ w3, const float* __restrict__ b3,
    const float* __restrict__ w4, const float* __restrict__ b4,
    float* __restrict__ out)
{
    __shared__ float sA[NF*PIT];
    __shared__ float sB[NF*PIT];
    __shared__ float sK[NF*PIT];
    __shared__ float sV[NF*PIT];
    __shared__ float sQ[NDH];
    __shared__ float sAtt[NF+1];
    __shared__ float sH1[128];
    __shared__ float sH2[64];

    const int r    = (int)blockIdx.x;
    const int lane = (int)threadIdx.x;

    // ---- embedding gather: e[f][d], lanes = 4 f's x 16 d's ----
    {
        const int fh = lane >> 4, d = lane & 15;
#pragma unroll
        for (int i = 0; i < 10; ++i){
            int f = i*4 + fh;
            if (f < NF){
                int idx = x[r*NF + f] + f*NVOC;
                sA[f*PIT + d] = emb[(size_t)idx*ND + d];
            }
        }
    }
    __syncthreads();

    attn_layer<ND >(sA, sB, sK, sV, sQ, sAtt, wq0, wk0, wv0, wr0, lane);
    attn_layer<NDH>(sB, sA, sK, sV, sQ, sAtt, wq1, wk1, wv1, wr1, lane);
    attn_layer<NDH>(sA, sB, sK, sV, sQ, sAtt, wq2, wk2, wv2, wr2, lane);
    // final e is in sB

    // ---- MLP1: 1248 -> 128 ; lane owns outputs 2*lane, 2*lane+1 (float2 load) ----
    {
        const float2* w1p = (const float2*)w1;
        float a0 = 0.f, a1 = 0.f;
        for (int f = 0; f < NF; ++f){
#pragma unroll
            for (int jj = 0; jj < NDH; ++jj){
                float h = sB[f*PIT + jj];                 // LDS broadcast
                float2 w = w1p[(f*NDH + jj)*64 + lane];   // coalesced, 8 B/lane
                a0 += h * w.x;
                a1 += h * w.y;
            }
        }
        a0 = fmaxf(a0 + b1[2*lane+0], 0.f);
        a1 = fmaxf(a1 + b1[2*lane+1], 0.f);
        sH1[2*lane+0] = a0;
        sH1[2*lane+1] = a1;
    }
    __syncthreads();

    // ---- MLP2: 128 -> 64 ; one output per lane ----
    {
        float a = 0.f;
#pragma unroll 16
        for (int d = 0; d < 128; ++d) a += sH1[d] * w2[d*64 + lane];
        sH2[lane] = fmaxf(a + b2[lane], 0.f);
    }
    __syncthreads();

    // ---- MLP3: 64 -> 32 (lanes < 32), then MLP4 dot + sigmoid ----
    float a3 = 0.f;
    if (lane < 32){
#pragma unroll 16
        for (int d = 0; d < 64; ++d) a3 += sH2[d] * w3[d*32 + lane];
        a3 = fmaxf(a3 + b3[lane], 0.f);
        a3 *= w4[lane];
    }
    float z = wsumf(a3);
    if (lane == 0){
        z += b4[0];
        out[r] = 1.f / (1.f + __expf(-z));
    }
}

extern "C" void kernel_launch(void* const* d_in, const int* in_sizes, int n_in,
                              void* d_out, int out_size, void* d_ws, size_t ws_size,
                              hipStream_t stream)
{
    (void)in_sizes; (void)n_in; (void)d_ws; (void)ws_size; (void)out_size;
    const int*   x   = (const int*)d_in[0];
    const float* emb = (const float*)d_in[1];
    autoint_fused<<<NB, 64, 0, stream>>>(
        x, emb,
        (const float*)d_in[2],  (const float*)d_in[3],  (const float*)d_in[4],  (const float*)d_in[5],
        (const float*)d_in[6],  (const float*)d_in[7],  (const float*)d_in[8],  (const float*)d_in[9],
        (const float*)d_in[10], (const float*)d_in[11], (const float*)d_in[12], (const float*)d_in[13],
        (const float*)d_in[14], (const float*)d_in[15], (const float*)d_in[16], (const float*)d_in[17],
        (const float*)d_in[18], (const float*)d_in[19], (const float*)d_in[20], (const float*)d_in[21],
        (float*)d_out);
}

// Round 3
// 1750.850 us; speedup vs baseline: 1.5964x; 1.5964x over previous
//
#include <hip/hip_runtime.h>
#include <math.h>

#define NB   16384
#define NF   39
#define ND   16
#define NDH  32
#define NVOC 10000
#define PIT  36          // LDS row pitch in floats: 144 B -> 16B-aligned float4 rows
#define RPB  4           // rows (waves) per block
#define ROWF (NF*PIT)    // 1404 floats per buffer
#define WLDS (3*ROWF + 128 + 64 + 12)   // 4416 floats per wave region (16B-aligned)

__device__ __forceinline__ void wave_sync(){
    asm volatile("s_waitcnt lgkmcnt(0)" ::: "memory");
}

__device__ __forceinline__ float wsumf(float v){
#pragma unroll
    for (int off = 32; off; off >>= 1) v += __shfl_xor(v, off, 64);
    return v;
}

// Per-lane projection: acc[e] = sum_d eRow[d] * w[d][e].
// eRow is the lane's own LDS row; w is a uniform global pointer -> weight
// loads are lane-invariant -> scalarized to s_load, FMA reads SGPR operand.
template<int DIN>
__device__ __forceinline__ void proj_row(const float* __restrict__ w,
                                         const float* eRow, float acc[NDH]){
#pragma unroll
    for (int e = 0; e < NDH; ++e) acc[e] = 0.f;
#pragma unroll 2
    for (int d = 0; d < DIN; d += 2){
        float2 ev = *(const float2*)(eRow + d);
        const float* w0 = w + d*NDH;
        const float* w1 = w0 + NDH;
#pragma unroll
        for (int e = 0; e < NDH; ++e) acc[e] = fmaf(ev.x, w0[e], acc[e]);
#pragma unroll
        for (int e = 0; e < NDH; ++e) acc[e] = fmaf(ev.y, w1[e], acc[e]);
    }
}

// One wave processes one row's attention layer. lane = position f (f < 39 active).
// E in/out lives in bufE (pitch PIT); K,V staged in bufK/bufV.
template<int DIN>
__device__ __forceinline__ void attn_layer(
    float* bufE, float* bufK, float* bufV,
    const float* __restrict__ wq, const float* __restrict__ wk,
    const float* __restrict__ wv, const float* __restrict__ wr, int lane)
{
    const int f = lane;
    const float* eRow = bufE + f*PIT;
    float acc[NDH];

    proj_row<DIN>(wk, eRow, acc);              // K row
    if (f < NF){
        float* kRow = bufK + f*PIT;
#pragma unroll
        for (int t = 0; t < NDH; t += 4)
            *(float4*)(kRow + t) = make_float4(acc[t], acc[t+1], acc[t+2], acc[t+3]);
    }
    proj_row<DIN>(wv, eRow, acc);              // V row
    if (f < NF){
        float* vRow = bufV + f*PIT;
#pragma unroll
        for (int t = 0; t < NDH; t += 4)
            *(float4*)(vRow + t) = make_float4(acc[t], acc[t+1], acc[t+2], acc[t+3]);
    }
    float Q[NDH]; proj_row<DIN>(wq, eRow, Q);  // Q row (kept in regs)
    float R[NDH]; proj_row<DIN>(wr, eRow, R);  // residual-proj row (kept in regs)
    wave_sync();                               // K,V visible to all lanes

    // flash-style softmax, no max subtraction: |logit| << 1 for this net
    float O[NDH];
#pragma unroll
    for (int e = 0; e < NDH; ++e) O[e] = 0.f;
    float sum = 0.f;
    for (int g = 0; g < NF; ++g){
        const float* kg = bufK + g*PIT;        // uniform address -> LDS broadcast
        const float* vg = bufV + g*PIT;
        float s0 = 0.f, s1 = 0.f, s2 = 0.f, s3 = 0.f;
#pragma unroll
        for (int t = 0; t < NDH; t += 4){
            float4 kk = *(const float4*)(kg + t);
            s0 = fmaf(Q[t+0], kk.x, s0); s1 = fmaf(Q[t+1], kk.y, s1);
            s2 = fmaf(Q[t+2], kk.z, s2); s3 = fmaf(Q[t+3], kk.w, s3);
        }
        float p = __expf((s0+s1) + (s2+s3));
        sum += p;
#pragma unroll
        for (int t = 0; t < NDH; t += 4){
            float4 vv = *(const float4*)(vg + t);
            O[t+0] = fmaf(p, vv.x, O[t+0]); O[t+1] = fmaf(p, vv.y, O[t+1]);
            O[t+2] = fmaf(p, vv.z, O[t+2]); O[t+3] = fmaf(p, vv.w, O[t+3]);
        }
    }
    float inv = 1.f / sum;
    if (f < NF){
        float* eo = bufE + f*PIT;              // bufE reusable: all reads done
#pragma unroll
        for (int t = 0; t < NDH; t += 4){
            float4 o;
            o.x = fmaxf(fmaf(O[t+0], inv, R[t+0]), 0.f);
            o.y = fmaxf(fmaf(O[t+1], inv, R[t+1]), 0.f);
            o.z = fmaxf(fmaf(O[t+2], inv, R[t+2]), 0.f);
            o.w = fmaxf(fmaf(O[t+3], inv, R[t+3]), 0.f);
            *(float4*)(eo + t) = o;
        }
    }
    wave_sync();
}

__global__ void __launch_bounds__(256, 2) autoint_v3(
    const int* __restrict__ x, const float* __restrict__ emb,
    const float* __restrict__ wq0, const float* __restrict__ wk0,
    const float* __restrict__ wv0, const float* __restrict__ wr0,
    const float* __restrict__ wq1, const float* __restrict__ wk1,
    const float* __restrict__ wv1, const float* __restrict__ wr1,
    const float* __restrict__ wq2, const float* __restrict__ wk2,
    const float* __restrict__ wv2, const float* __restrict__ wr2,
    const float* __restrict__ w1, const float* __restrict__ b1,
    const float* __restrict__ w2, const float* __restrict__ b2,
    const float* __restrict__ w3, const float* __restrict__ b3,
    const float* __restrict__ w4, const float* __restrict__ b4,
    float* __restrict__ out)
{
    __shared__ float lds[RPB*WLDS];
    const int wid  = (int)threadIdx.x >> 6;
    const int lane = (int)threadIdx.x & 63;
    const int r    = (int)blockIdx.x * RPB + wid;

    float* bufE = lds + wid*WLDS;
    float* bufK = bufE + ROWF;
    float* bufV = bufK + ROWF;
    float* H1   = bufV + ROWF;
    float* H2   = H1 + 128;

    // ---- embedding gather: lane f loads its 16-float row ----
    if (lane < NF){
        int idx = x[r*NF + lane] + lane*NVOC;
        const float4* ep = (const float4*)(emb + (size_t)idx*ND);
        float4* dst = (float4*)(bufE + lane*PIT);
        dst[0] = ep[0]; dst[1] = ep[1]; dst[2] = ep[2]; dst[3] = ep[3];
    }
    wave_sync();

    attn_layer<ND>(bufE, bufK, bufV, wq0, wk0, wv0, wr0, lane);
    {
        const float* WQ[2] = {wq1, wq2}; const float* WK[2] = {wk1, wk2};
        const float* WV[2] = {wv1, wv2}; const float* WR[2] = {wr1, wr2};
#pragma unroll 1
        for (int L = 0; L < 2; ++L)
            attn_layer<NDH>(bufE, bufK, bufV, WQ[L], WK[L], WV[L], WR[L], lane);
    }

    __syncthreads();   // align the 4 waves so they stream w1 together (L1 reuse)

    // ---- MLP1: 1248 -> 128 ; lane owns cols {2*lane, 2*lane+1} ----
    {
        const float2* w1p = (const float2*)w1;
        float a0 = 0.f, a1 = 0.f;
        for (int ff = 0; ff < NF; ++ff){
            const float* hRow = bufE + ff*PIT;
#pragma unroll
            for (int c = 0; c < NDH; c += 4){
                float4 h4 = *(const float4*)(hRow + c);         // LDS broadcast
                float2 wa = w1p[(ff*NDH + c + 0)*64 + lane];    // coalesced 8B
                float2 wb = w1p[(ff*NDH + c + 1)*64 + lane];
                float2 wc = w1p[(ff*NDH + c + 2)*64 + lane];
                float2 wd = w1p[(ff*NDH + c + 3)*64 + lane];
                a0 = fmaf(h4.x, wa.x, a0); a1 = fmaf(h4.x, wa.y, a1);
                a0 = fmaf(h4.y, wb.x, a0); a1 = fmaf(h4.y, wb.y, a1);
                a0 = fmaf(h4.z, wc.x, a0); a1 = fmaf(h4.z, wc.y, a1);
                a0 = fmaf(h4.w, wd.x, a0); a1 = fmaf(h4.w, wd.y, a1);
            }
        }
        a0 = fmaxf(a0 + b1[2*lane+0], 0.f);
        a1 = fmaxf(a1 + b1[2*lane+1], 0.f);
        *(float2*)(H1 + 2*lane) = make_float2(a0, a1);
    }
    wave_sync();

    // ---- MLP2: 128 -> 64 ----
    {
        float a = 0.f;
#pragma unroll 4
        for (int d = 0; d < 128; d += 4){
            float4 h4 = *(const float4*)(H1 + d);               // broadcast
            a = fmaf(h4.x, w2[(d+0)*64 + lane], a);
            a = fmaf(h4.y, w2[(d+1)*64 + lane], a);
            a = fmaf(h4.z, w2[(d+2)*64 + lane], a);
            a = fmaf(h4.w, w2[(d+3)*64 + lane], a);
        }
        H2[lane] = fmaxf(a + b2[lane], 0.f);
    }
    wave_sync();

    // ---- MLP3: 64 -> 32 (lanes < 32), fused MLP4 dot + sigmoid ----
    float a3 = 0.f;
    if (lane < 32){
#pragma unroll 4
        for (int d = 0; d < 64; d += 4){
            float4 h4 = *(const float4*)(H2 + d);               // broadcast
            a3 = fmaf(h4.x, w3[(d+0)*32 + lane], a3);
            a3 = fmaf(h4.y, w3[(d+1)*32 + lane], a3);
            a3 = fmaf(h4.z, w3[(d+2)*32 + lane], a3);
            a3 = fmaf(h4.w, w3[(d+3)*32 + lane], a3);
        }
        a3 = fmaxf(a3 + b3[lane], 0.f) * w4[lane];
    }
    float z = wsumf(a3);
    if (lane == 0){
        z += b4[0];
        out[r] = 1.f / (1.f + __expf(-z));
    }
}

extern "C" void kernel_launch(void* const* d_in, const int* in_sizes, int n_in,
                              void* d_out, int out_size, void* d_ws, size_t ws_size,
                              hipStream_t stream)
{
    (void)in_sizes; (void)n_in; (void)d_ws; (void)ws_size; (void)out_size;
    const int*   x   = (const int*)d_in[0];
    const float* emb = (const float*)d_in[1];
    autoint_v3<<<NB/RPB, 256, 0, stream>>>(
        x, emb,
        (const float*)d_in[2],  (const float*)d_in[3],  (const float*)d_in[4],  (const float*)d_in[5],
        (const float*)d_in[6],  (const float*)d_in[7],  (const float*)d_in[8],  (const float*)d_in[9],
        (const float*)d_in[10], (const float*)d_in[11], (const float*)d_in[12], (const float*)d_in[13],
        (const float*)d_in[14], (const float*)d_in[15], (const float*)d_in[16], (const float*)d_in[17],
        (const float*)d_in[18], (const float*)d_in[19], (const float*)d_in[20], (const float*)d_in[21],
        (float*)d_out);
}

// Round 4
// 225.089 us; speedup vs baseline: 12.4177x; 7.7785x over previous
//
#include <hip/hip_runtime.h>
#include <math.h>

#define NF   39
#define NB   16384
#define NVOC 10000

typedef float f32x4 __attribute__((ext_vector_type(4)));
typedef short s16x8 __attribute__((ext_vector_type(8)));

// ---- d_ws layout (u16 units) ----
// [0, E3_U16): E3 activations, A-fragment tiles: (sample_tile st, kstep f) -> 512 u16
//   element (sample m, feat e): (st*39+f)*512 + ((m&15) + 16*(e>>3))*8 + (e&7)
// [E3_U16 ...): weights in B-fragment tiles (512 u16 each):
//   12 attn mats (q,k,v,r × 3 layers) × 2 nt-tiles            = 12288
//   W1 [1248][128]: (ks*8+nt) tiles, ks=0..38, nt=0..7        = 159744
//   W2 [128][64]:   (ks*4+nt), ks=0..3, nt=0..3               = 8192
//   W3 [64][32]:    (ks*2+nt), ks=0..1, nt=0..1               = 2048
#define E3_U16   20447232u
#define NSWZ     182272

__device__ __forceinline__ unsigned short f2bf(float f){
    union { float f; unsigned int i; } c; c.f = f;
    unsigned int r = c.i + 0x7fffu + ((c.i >> 16) & 1u);
    return (unsigned short)(r >> 16);
}
__device__ __forceinline__ void wave_sync(){
    asm volatile("s_waitcnt lgkmcnt(0)" ::: "memory");
}
__device__ __forceinline__ f32x4 mfma16(s16x8 a, s16x8 b, f32x4 c){
    return __builtin_amdgcn_mfma_f32_16x16x32_bf16(a, b, c, 0, 0, 0);
}

// ================= K0: weight pre-swizzle =================
__global__ void __launch_bounds__(256) swz_kernel(
    const float* __restrict__ wq0, const float* __restrict__ wk0,
    const float* __restrict__ wv0, const float* __restrict__ wr0,
    const float* __restrict__ wq1, const float* __restrict__ wk1,
    const float* __restrict__ wv1, const float* __restrict__ wr1,
    const float* __restrict__ wq2, const float* __restrict__ wk2,
    const float* __restrict__ wv2, const float* __restrict__ wr2,
    const float* __restrict__ w1, const float* __restrict__ w2,
    const float* __restrict__ w3, unsigned short* __restrict__ ws)
{
    int gid = (int)blockIdx.x*256 + (int)threadIdx.x;
    if (gid >= NSWZ) return;
    int w    = gid & 511;
    int lane = w >> 3, j = w & 7;
    int n    = lane & 15, quad = lane >> 4;
    int kin  = quad*8 + j;               // k within a 32-deep kstep
    float val;
    if (gid < 12288){
        int mat = gid >> 10;
        int nt  = (gid >> 9) & 1;
        const float* W;
        switch (mat){
            case 0: W = wq0; break; case 1: W = wk0; break;
            case 2: W = wv0; break; case 3: W = wr0; break;
            case 4: W = wq1; break; case 5: W = wk1; break;
            case 6: W = wv1; break; case 7: W = wr1; break;
            case 8: W = wq2; break; case 9: W = wk2; break;
            case 10: W = wv2; break; default: W = wr2; break;
        }
        int din = (mat < 4) ? 16 : 32;
        val = (kin < din) ? W[kin*32 + nt*16 + n] : 0.f;
    } else if (gid < 12288 + 159744){
        int tt = (gid - 12288) >> 9;
        int ks = tt >> 3, nt = tt & 7;
        val = w1[(ks*32 + kin)*128 + nt*16 + n];
    } else if (gid < 12288 + 159744 + 8192){
        int tt = (gid - (12288+159744)) >> 9;
        int ks = tt >> 2, nt = tt & 3;
        val = w2[(ks*32 + kin)*64 + nt*16 + n];
    } else {
        int tt = (gid - (12288+159744+8192)) >> 9;
        int ks = tt >> 1, nt = tt & 1;
        val = w3[(ks*32 + kin)*32 + nt*16 + n];
    }
    ws[E3_U16 + gid] = f2bf(val);
}

// ================= K1: fused attention (3 layers) =================
// One wave per sample. LDS per wave (u16): E 1536 | K 1536 | Q 1536 | V 2048
// (P overlays K+Q).  All fragment reads are ds_read_b128 at lane*16B.
__device__ __forceinline__ void proj4(const s16x8 aE[3], const unsigned short* wp_lane,
                                      f32x4 c[3][2]){
    const f32x4 z = {0.f,0.f,0.f,0.f};
#pragma unroll
    for (int nt = 0; nt < 2; ++nt){
        s16x8 b = *(const s16x8*)(wp_lane + nt*512);
#pragma unroll
        for (int mt = 0; mt < 3; ++mt) c[mt][nt] = mfma16(aE[mt], b, z);
    }
}

__global__ void __launch_bounds__(256, 3) attn_kernel(
    const int* __restrict__ x, const float* __restrict__ emb,
    unsigned short* __restrict__ ws)
{
    __shared__ __align__(16) unsigned short lds[4*6656];
    const int tid  = (int)threadIdx.x;
    const int wid  = tid >> 6, lane = tid & 63;
    const int h    = lane >> 4, nl = lane & 15;
    const int r    = (int)blockIdx.x*4 + wid;

    unsigned short* eBuf = lds + wid*6656;   // 1536: E A-tiles (mt 0..2)
    unsigned short* kBuf = eBuf + 1536;      // 1536: K^T B-tiles (ntg 0..2)
    unsigned short* qBuf = kBuf + 1536;      // 1536: Q A-tiles
    unsigned short* pBuf = kBuf;             // 3072: P A-tiles (mt,ks) overlays K+Q
    unsigned short* vBuf = qBuf + 1536;      // 2048: V B-tiles (ks,nt)
    const unsigned short* wmat = ws + E3_U16;
    const s16x8 zv = {0,0,0,0,0,0,0,0};

    // ---- embedding gather -> E A-layout (rows 39..47 and k 16..31 zeroed) ----
    if (lane < 48){
        int f = lane, mt = f >> 4, fl = f & 15;
        unsigned short* row = eBuf + mt*512 + fl*8;
        if (f < NF){
            const float4* ep = (const float4*)(emb + ((size_t)(x[r*NF + f] + f*NVOC))*16);
            float4 e0 = ep[0], e1 = ep[1], e2 = ep[2], e3 = ep[3];
            s16x8 lo, hi;
            lo[0]=(short)f2bf(e0.x); lo[1]=(short)f2bf(e0.y); lo[2]=(short)f2bf(e0.z); lo[3]=(short)f2bf(e0.w);
            lo[4]=(short)f2bf(e1.x); lo[5]=(short)f2bf(e1.y); lo[6]=(short)f2bf(e1.z); lo[7]=(short)f2bf(e1.w);
            hi[0]=(short)f2bf(e2.x); hi[1]=(short)f2bf(e2.y); hi[2]=(short)f2bf(e2.z); hi[3]=(short)f2bf(e2.w);
            hi[4]=(short)f2bf(e3.x); hi[5]=(short)f2bf(e3.y); hi[6]=(short)f2bf(e3.z); hi[7]=(short)f2bf(e3.w);
            *(s16x8*)(row)       = lo;
            *(s16x8*)(row + 128) = hi;
        } else {
            *(s16x8*)(row)       = zv;
            *(s16x8*)(row + 128) = zv;
        }
        *(s16x8*)(row + 256) = zv;   // k 16..23
        *(s16x8*)(row + 384) = zv;   // k 24..31
    }
    wave_sync();

#pragma unroll 1
    for (int L = 0; L < 3; ++L){
        const unsigned short* wL = wmat + L*4096 + lane*8;
        s16x8 aE[3];
#pragma unroll
        for (int mt = 0; mt < 3; ++mt) aE[mt] = *(const s16x8*)(eBuf + mt*512 + lane*8);
        // zero V pad rows g=48..63 (k-local 16..31 of kstep-1 tiles)
        if (h >= 2){
            *(s16x8*)(vBuf + 2*512 + lane*8) = zv;
            *(s16x8*)(vBuf + 3*512 + lane*8) = zv;
        }
        // ---- K projection -> K^T B-layout: B[k=e][n=g] ----
        {
            f32x4 c[3][2]; proj4(aE, wL + 1024, c);
#pragma unroll
            for (int mt = 0; mt < 3; ++mt)
#pragma unroll
            for (int nt = 0; nt < 2; ++nt)
#pragma unroll
            for (int reg = 0; reg < 4; ++reg){
                int e = nt*16 + nl;
                kBuf[mt*512 + ((h*4+reg) + ((e>>3)<<4))*8 + (e&7)] = f2bf(c[mt][nt][reg]);
            }
        }
        // ---- V projection -> V B-layout: B[k=g][n=e] ----
        {
            f32x4 c[3][2]; proj4(aE, wL + 2048, c);
#pragma unroll
            for (int mt = 0; mt < 3; ++mt)
#pragma unroll
            for (int nt = 0; nt < 2; ++nt)
#pragma unroll
            for (int reg = 0; reg < 4; ++reg){
                vBuf[((mt>>1)*2 + nt)*512 + (nl + (((mt&1)*2 + (h>>1))<<4))*8 + (h&1)*4 + reg]
                    = f2bf(c[mt][nt][reg]);
            }
        }
        // ---- Q projection -> Q A-layout: A[m=f][k=e] ----
        {
            f32x4 c[3][2]; proj4(aE, wL, c);
#pragma unroll
            for (int mt = 0; mt < 3; ++mt)
#pragma unroll
            for (int nt = 0; nt < 2; ++nt)
#pragma unroll
            for (int reg = 0; reg < 4; ++reg){
                int e = nt*16 + nl;
                qBuf[mt*512 + ((h*4+reg) + ((e>>3)<<4))*8 + (e&7)] = f2bf(c[mt][nt][reg]);
            }
        }
        // ---- R projection -> keep in C-layout regs ----
        f32x4 R[3][2]; proj4(aE, wL + 3072, R);
        wave_sync();

        // ---- S = Q @ K^T  (9 MFMAs) ----
        f32x4 S[3][3];
        {
            s16x8 qa[3], kb[3];
#pragma unroll
            for (int mt = 0; mt < 3; ++mt) qa[mt] = *(const s16x8*)(qBuf + mt*512 + lane*8);
#pragma unroll
            for (int ng = 0; ng < 3; ++ng) kb[ng] = *(const s16x8*)(kBuf + ng*512 + lane*8);
            const f32x4 z = {0.f,0.f,0.f,0.f};
#pragma unroll
            for (int mt = 0; mt < 3; ++mt)
#pragma unroll
            for (int ng = 0; ng < 3; ++ng) S[mt][ng] = mfma16(qa[mt], kb[ng], z);
        }
        // ---- masked softmax (fp32), rowsum via 16-lane shuffle ----
        float inv[3][4];
#pragma unroll
        for (int mt = 0; mt < 3; ++mt){
#pragma unroll
            for (int ng = 0; ng < 3; ++ng){
                int g = ng*16 + nl;
#pragma unroll
                for (int reg = 0; reg < 4; ++reg)
                    S[mt][ng][reg] = (g < NF) ? __expf(S[mt][ng][reg]) : 0.f;
            }
#pragma unroll
            for (int reg = 0; reg < 4; ++reg){
                float t = S[mt][0][reg] + S[mt][1][reg] + S[mt][2][reg];
                t += __shfl_xor(t, 1, 64);
                t += __shfl_xor(t, 2, 64);
                t += __shfl_xor(t, 4, 64);
                t += __shfl_xor(t, 8, 64);
                inv[mt][reg] = 1.0f / t;
            }
        }
        // ---- P -> A-layout (overlays K+Q); zero pad k=48..63 first ----
        if (h >= 2){
#pragma unroll
            for (int mt = 0; mt < 3; ++mt)
                *(s16x8*)(pBuf + (mt*2+1)*512 + lane*8) = zv;
        }
#pragma unroll
        for (int mt = 0; mt < 3; ++mt)
#pragma unroll
        for (int ng = 0; ng < 3; ++ng)
#pragma unroll
        for (int reg = 0; reg < 4; ++reg){
            int idx = (mt*2 + (ng>>1))*512
                    + ((h*4+reg) + (((ng&1)*2 + (nl>>3))<<4))*8 + (nl&7);
            pBuf[idx] = f2bf(S[mt][ng][reg] * inv[mt][reg]);
        }
        wave_sync();

        // ---- O = P @ V  (12 MFMAs) ----
        f32x4 O[3][2];
        {
            s16x8 pa[3][2], vb[2][2];
#pragma unroll
            for (int mt = 0; mt < 3; ++mt)
#pragma unroll
            for (int ks = 0; ks < 2; ++ks)
                pa[mt][ks] = *(const s16x8*)(pBuf + (mt*2+ks)*512 + lane*8);
#pragma unroll
            for (int ks = 0; ks < 2; ++ks)
#pragma unroll
            for (int nt = 0; nt < 2; ++nt)
                vb[ks][nt] = *(const s16x8*)(vBuf + (ks*2+nt)*512 + lane*8);
            const f32x4 z = {0.f,0.f,0.f,0.f};
#pragma unroll
            for (int mt = 0; mt < 3; ++mt)
#pragma unroll
            for (int nt = 0; nt < 2; ++nt)
                O[mt][nt] = mfma16(pa[mt][1], vb[1][nt], mfma16(pa[mt][0], vb[0][nt], z));
        }
        // ---- epilogue: relu(O + R) -> E (LDS) or E3 (global A-layout) ----
        if (L < 2){
#pragma unroll
            for (int mt = 0; mt < 3; ++mt)
#pragma unroll
            for (int nt = 0; nt < 2; ++nt)
#pragma unroll
            for (int reg = 0; reg < 4; ++reg){
                int f = mt*16 + h*4 + reg;
                if (f < NF){
                    int e = nt*16 + nl;
                    float v = fmaxf(O[mt][nt][reg] + R[mt][nt][reg], 0.f);
                    eBuf[mt*512 + ((h*4+reg) + ((e>>3)<<4))*8 + (e&7)] = f2bf(v);
                }
            }
        } else {
            int st = r >> 4, sm = r & 15;
#pragma unroll
            for (int mt = 0; mt < 3; ++mt)
#pragma unroll
            for (int nt = 0; nt < 2; ++nt)
#pragma unroll
            for (int reg = 0; reg < 4; ++reg){
                int f = mt*16 + h*4 + reg;
                if (f < NF){
                    int e = nt*16 + nl;
                    float v = fmaxf(O[mt][nt][reg] + R[mt][nt][reg], 0.f);
                    ws[(unsigned)(st*39 + f)*512u + (sm + ((e>>3)<<4))*8 + (e&7)] = f2bf(v);
                }
            }
        }
        wave_sync();
    }
}

// ================= K2: MLP 1248->128->64->32->1 =================
__global__ void __launch_bounds__(256) mlp_kernel(
    const float* __restrict__ b1, const float* __restrict__ b2,
    const float* __restrict__ b3, const float* __restrict__ w4,
    const float* __restrict__ b4, const unsigned short* __restrict__ ws,
    float* __restrict__ out)
{
    __shared__ __align__(16) unsigned short h1[4*2048];  // per-wave A-tiles for GEMM2
    __shared__ __align__(16) unsigned short h2[4*1024];  // per-wave A-tiles for GEMM3
    const int tid = (int)threadIdx.x;
    const int wid = tid >> 6, lane = tid & 63;
    const int h   = lane >> 4, nl = lane & 15;
    const int st  = (int)blockIdx.x*4 + wid;             // sample tile (16 samples)

    const unsigned short* e3  = ws;
    const unsigned short* w1b = ws + E3_U16 + 12288u;
    const unsigned short* w2b = w1b + 159744u;
    const unsigned short* w3b = w2b + 8192u;
    const f32x4 z = {0.f,0.f,0.f,0.f};

    // ---- GEMM1: [16,1248] @ [1248,128] ----
    f32x4 acc[8];
#pragma unroll
    for (int nt = 0; nt < 8; ++nt) acc[nt] = z;
#pragma unroll 1
    for (int ks = 0; ks < 39; ++ks){
        s16x8 a = *(const s16x8*)(e3 + (unsigned)(st*39 + ks)*512u + lane*8);
#pragma unroll
        for (int nt = 0; nt < 8; ++nt){
            s16x8 b = *(const s16x8*)(w1b + (ks*8 + nt)*512 + lane*8);
            acc[nt] = mfma16(a, b, acc[nt]);
        }
    }
#pragma unroll
    for (int nt = 0; nt < 8; ++nt){
        float bb = b1[nt*16 + nl];
#pragma unroll
        for (int reg = 0; reg < 4; ++reg){
            float v = fmaxf(acc[nt][reg] + bb, 0.f);
            int m = h*4 + reg, k = nt*16 + nl;
            h1[wid*2048 + (k>>5)*512 + (m + (((k>>3)&3)<<4))*8 + (k&7)] = f2bf(v);
        }
    }
    wave_sync();
    // ---- GEMM2: [16,128] @ [128,64] ----
    f32x4 acc2[4];
#pragma unroll
    for (int nt = 0; nt < 4; ++nt) acc2[nt] = z;
#pragma unroll
    for (int ks = 0; ks < 4; ++ks){
        s16x8 a = *(const s16x8*)(h1 + wid*2048 + ks*512 + lane*8);
#pragma unroll
        for (int nt = 0; nt < 4; ++nt){
            s16x8 b = *(const s16x8*)(w2b + (ks*4 + nt)*512 + lane*8);
            acc2[nt] = mfma16(a, b, acc2[nt]);
        }
    }
#pragma unroll
    for (int nt = 0; nt < 4; ++nt){
        float bb = b2[nt*16 + nl];
#pragma unroll
        for (int reg = 0; reg < 4; ++reg){
            float v = fmaxf(acc2[nt][reg] + bb, 0.f);
            int m = h*4 + reg, k = nt*16 + nl;
            h2[wid*1024 + (k>>5)*512 + (m + (((k>>3)&3)<<4))*8 + (k&7)] = f2bf(v);
        }
    }
    wave_sync();
    // ---- GEMM3: [16,64] @ [64,32] ----
    f32x4 acc3[2];
    acc3[0] = z; acc3[1] = z;
#pragma unroll
    for (int ks = 0; ks < 2; ++ks){
        s16x8 a = *(const s16x8*)(h2 + wid*1024 + ks*512 + lane*8);
#pragma unroll
        for (int nt = 0; nt < 2; ++nt){
            s16x8 b = *(const s16x8*)(w3b + (ks*2 + nt)*512 + lane*8);
            acc3[nt] = mfma16(a, b, acc3[nt]);
        }
    }
    // ---- MLP4 dot + sigmoid ----
    float w4a = w4[nl], w4b = w4[16 + nl];
    float b3a = b3[nl], b3b = b3[16 + nl];
    float bb4 = b4[0];
#pragma unroll
    for (int reg = 0; reg < 4; ++reg){
        float t = fmaxf(acc3[0][reg] + b3a, 0.f)*w4a
                + fmaxf(acc3[1][reg] + b3b, 0.f)*w4b;
        t += __shfl_xor(t, 1, 64);
        t += __shfl_xor(t, 2, 64);
        t += __shfl_xor(t, 4, 64);
        t += __shfl_xor(t, 8, 64);
        if (nl == 0)
            out[st*16 + h*4 + reg] = 1.f/(1.f + __expf(-(t + bb4)));
    }
}

extern "C" void kernel_launch(void* const* d_in, const int* in_sizes, int n_in,
                              void* d_out, int out_size, void* d_ws, size_t ws_size,
                              hipStream_t stream)
{
    (void)in_sizes; (void)n_in; (void)ws_size; (void)out_size;
    const int*   x   = (const int*)d_in[0];
    const float* emb = (const float*)d_in[1];
    unsigned short* ws = (unsigned short*)d_ws;

    swz_kernel<<<NSWZ/256, 256, 0, stream>>>(
        (const float*)d_in[2],  (const float*)d_in[3],  (const float*)d_in[4],  (const float*)d_in[5],
        (const float*)d_in[6],  (const float*)d_in[7],  (const float*)d_in[8],  (const float*)d_in[9],
        (const float*)d_in[10], (const float*)d_in[11], (const float*)d_in[12], (const float*)d_in[13],
        (const float*)d_in[14], (const float*)d_in[16], (const float*)d_in[18], ws);

    attn_kernel<<<NB/4, 256, 0, stream>>>(x, emb, ws);

    mlp_kernel<<<NB/64, 256, 0, stream>>>(
        (const float*)d_in[15], (const float*)d_in[17], (const float*)d_in[19],
        (const float*)d_in[20], (const float*)d_in[21], ws, (float*)d_out);
}

// Round 5
// 195.348 us; speedup vs baseline: 14.3082x; 1.1522x over previous
//
#include <hip/hip_runtime.h>
#include <math.h>

#define NF   39
#define NB   16384
#define NVOC 10000

typedef unsigned short u16;
typedef unsigned int   u32;
typedef float f32x4 __attribute__((ext_vector_type(4)));
typedef short s16x8 __attribute__((ext_vector_type(8)));

// ---- d_ws layout (u16 units) ----
// [0, E3_U16): E3 activations, A-fragment tiles: (st, ks=f) -> 512 u16
// [E3_U16 ...): weights as 512-u16 fragment tiles:
//   12 attn mats (q,k,v,r × 3 layers) × 2 tiles = 12288
//   W1: (ks*8+nt), ks<39, nt<8  = 159744      W2: (ks*4+nt), ks<4, nt<4 = 8192
//   W3: (ks*2+nt), ks<2, nt<2   = 2048
#define E3_U16   20447232u
#define NSWZ     182272

__device__ __forceinline__ u32 bfadj(float x){
    u32 u = __float_as_uint(x);
    return u + 0x7fffu + ((u >> 16) & 1u);
}
// pack two fp32 -> two RNE bf16 in one u32 (low = a, high = b)
__device__ __forceinline__ u32 pk2(float a, float b){
    return __builtin_amdgcn_perm(bfadj(a), bfadj(b), 0x03020706u);
}
__device__ __forceinline__ u16 f2bf(float f){ return (u16)(bfadj(f) >> 16); }

__device__ __forceinline__ void wave_sync(){
    asm volatile("s_waitcnt lgkmcnt(0)" ::: "memory");
}
__device__ __forceinline__ f32x4 mfma16(s16x8 a, s16x8 b, f32x4 c){
    return __builtin_amdgcn_mfma_f32_16x16x32_bf16(a, b, c, 0, 0, 0);
}
// store 4 consecutive-k accumulator regs as packed bf16 (8 B)
__device__ __forceinline__ void store4(u16* p, f32x4 v){
    *(uint2*)p = make_uint2(pk2(v[0], v[1]), pk2(v[2], v[3]));
}

// ================= K0: weight pre-swizzle (unchanged layout) =================
__global__ void __launch_bounds__(256) swz_kernel(
    const float* __restrict__ wq0, const float* __restrict__ wk0,
    const float* __restrict__ wv0, const float* __restrict__ wr0,
    const float* __restrict__ wq1, const float* __restrict__ wk1,
    const float* __restrict__ wv1, const float* __restrict__ wr1,
    const float* __restrict__ wq2, const float* __restrict__ wk2,
    const float* __restrict__ wv2, const float* __restrict__ wr2,
    const float* __restrict__ w1, const float* __restrict__ w2,
    const float* __restrict__ w3, u16* __restrict__ ws)
{
    int gid = (int)blockIdx.x*256 + (int)threadIdx.x;
    if (gid >= NSWZ) return;
    int w    = gid & 511;
    int lane = w >> 3, j = w & 7;
    int n    = lane & 15, quad = lane >> 4;
    int kin  = quad*8 + j;
    float val;
    if (gid < 12288){
        int mat = gid >> 10;
        int nt  = (gid >> 9) & 1;
        const float* W;
        switch (mat){
            case 0: W = wq0; break; case 1: W = wk0; break;
            case 2: W = wv0; break; case 3: W = wr0; break;
            case 4: W = wq1; break; case 5: W = wk1; break;
            case 6: W = wv1; break; case 7: W = wr1; break;
            case 8: W = wq2; break; case 9: W = wk2; break;
            case 10: W = wv2; break; default: W = wr2; break;
        }
        int din = (mat < 4) ? 16 : 32;
        val = (kin < din) ? W[kin*32 + nt*16 + n] : 0.f;
    } else if (gid < 12288 + 159744){
        int tt = (gid - 12288) >> 9;
        int ks = tt >> 3, nt = tt & 7;
        val = w1[(ks*32 + kin)*128 + nt*16 + n];
    } else if (gid < 12288 + 159744 + 8192){
        int tt = (gid - (12288+159744)) >> 9;
        int ks = tt >> 2, nt = tt & 3;
        val = w2[(ks*32 + kin)*64 + nt*16 + n];
    } else {
        int tt = (gid - (12288+159744+8192)) >> 9;
        int ks = tt >> 1, nt = tt & 1;
        val = w3[(ks*32 + kin)*32 + nt*16 + n];
    }
    ws[E3_U16 + gid] = f2bf(val);
}

// ================= K1: fused attention, transpose-oriented =================
// One wave per sample. All GEMMs oriented so C-rows = consumer fragment k-dim:
//   Q^T = wq^T x E^T, K^T = wk^T x E^T, R^T = wr^T x E^T, V = E x wv,
//   S^T = K x Q^T (A=kBuf, B=qBuf), O^T = V^T x P^T (A=vBuf, B=pBuf).
// Every epilogue: per (tile) one packed ds_write_b64 at A_off.
__global__ void __launch_bounds__(256, 3) attn_kernel(
    const int* __restrict__ x, const float* __restrict__ emb,
    u16* __restrict__ ws)
{
    __shared__ __align__(16) u16 lds[4*6656];
    const int tid  = (int)threadIdx.x;
    const int wid  = tid >> 6, lane = tid & 63;
    const int h    = lane >> 4, nl = lane & 15;
    const int r    = (int)blockIdx.x*4 + wid;

    u16* eBuf = lds + wid*6656;   // 1536: E  (A-frag of E == B-frag of E^T), 3 f-tiles
    u16* kBuf = eBuf + 1536;      // 1536: K  (A-frag of K == B-frag of K^T), 3 g-tiles
    u16* qBuf = kBuf + 1536;      // 1536: Q^T B-frag, 3 f-tiles
    u16* vBuf = qBuf + 1536;      // 2048: V B-frag (ks,emt), 4 tiles
    u16* pBuf = kBuf;             // 3072: P^T B-frag (ks*3+nt), overlays K+Q
    const u16* wmat = ws + E3_U16;
    const f32x4 z = {0.f, 0.f, 0.f, 0.f};
    const int A_off = nl*8 + (h>>1)*128 + (h&1)*4;

    // S^T C-init: pad rows g>=39 (only in mtg=2 tile: g = 32+h*4+reg)
    f32x4 ci;
#pragma unroll
    for (int reg = 0; reg < 4; ++reg)
        ci[reg] = (h*4 + reg >= 7) ? -1e30f : 0.f;

    // ---- embedding gather -> E A-frag (rows f>=39 zero, k 16..31 zero) ----
    if (lane < 48){
        int f = lane, mt = f >> 4, fl = f & 15;
        u16* row = eBuf + mt*512 + fl*8;
        if (f < NF){
            const float4* ep = (const float4*)(emb + ((size_t)(x[r*NF + f] + f*NVOC))*16);
            float4 e0 = ep[0], e1 = ep[1], e2 = ep[2], e3 = ep[3];
            *(uint4*)(row)       = make_uint4(pk2(e0.x,e0.y), pk2(e0.z,e0.w),
                                              pk2(e1.x,e1.y), pk2(e1.z,e1.w));
            *(uint4*)(row + 128) = make_uint4(pk2(e2.x,e2.y), pk2(e2.z,e2.w),
                                              pk2(e3.x,e3.y), pk2(e3.z,e3.w));
        } else {
            *(uint4*)(row)       = make_uint4(0,0,0,0);
            *(uint4*)(row + 128) = make_uint4(0,0,0,0);
        }
        *(uint4*)(row + 256) = make_uint4(0,0,0,0);
        *(uint4*)(row + 384) = make_uint4(0,0,0,0);
    }
    wave_sync();

#pragma unroll 1
    for (int L = 0; L < 3; ++L){
        const u16* wB = wmat + L*4096;
        s16x8 bE[3];
#pragma unroll
        for (int nt = 0; nt < 3; ++nt)
            bE[nt] = *(const s16x8*)(eBuf + nt*512 + lane*8);

        // ---- Q^T -> qBuf ----
        {
            s16x8 a0 = *(const s16x8*)(wB + lane*8);
            s16x8 a1 = *(const s16x8*)(wB + 512 + lane*8);
#pragma unroll
            for (int nt = 0; nt < 3; ++nt){
                store4(qBuf + nt*512       + A_off, mfma16(a0, bE[nt], z));
                store4(qBuf + nt*512 + 256 + A_off, mfma16(a1, bE[nt], z));
            }
        }
        // ---- K^T -> kBuf ----
        {
            s16x8 a0 = *(const s16x8*)(wB + 1024 + lane*8);
            s16x8 a1 = *(const s16x8*)(wB + 1536 + lane*8);
#pragma unroll
            for (int nt = 0; nt < 3; ++nt){
                store4(kBuf + nt*512       + A_off, mfma16(a0, bE[nt], z));
                store4(kBuf + nt*512 + 256 + A_off, mfma16(a1, bE[nt], z));
            }
        }
        // ---- V -> vBuf (normal orientation: rows g) ----
        {
            s16x8 b0 = *(const s16x8*)(wB + 2048 + lane*8);
            s16x8 b1 = *(const s16x8*)(wB + 2560 + lane*8);
#pragma unroll
            for (int mtg = 0; mtg < 3; ++mtg){
                int toff = (mtg>>1)*1024 + (mtg&1)*256;
                store4(vBuf + toff       + A_off, mfma16(bE[mtg], b0, z));
                store4(vBuf + toff + 512 + A_off, mfma16(bE[mtg], b1, z));
            }
            // zero V pad rows g=48..63 (ks=1 tiles, k-local 16..31)
            *(uint2*)(vBuf + 2*512 + 256 + lane*4) = make_uint2(0,0);
            *(uint2*)(vBuf + 3*512 + 256 + lane*4) = make_uint2(0,0);
        }
        // ---- R^T in regs (rows e, cols f — matches O^T) ----
        f32x4 R[2][3];
        {
            s16x8 a0 = *(const s16x8*)(wB + 3072 + lane*8);
            s16x8 a1 = *(const s16x8*)(wB + 3584 + lane*8);
#pragma unroll
            for (int nt = 0; nt < 3; ++nt){
                R[0][nt] = mfma16(a0, bE[nt], z);
                R[1][nt] = mfma16(a1, bE[nt], z);
            }
        }
        wave_sync();

        // ---- S^T = K x Q^T (9 MFMAs), pad rows killed by ci ----
        f32x4 S[3][3];
        {
            s16x8 aK[3], bQ[3];
#pragma unroll
            for (int i = 0; i < 3; ++i){
                aK[i] = *(const s16x8*)(kBuf + i*512 + lane*8);
                bQ[i] = *(const s16x8*)(qBuf + i*512 + lane*8);
            }
#pragma unroll
            for (int mtg = 0; mtg < 3; ++mtg)
#pragma unroll
            for (int nt = 0; nt < 3; ++nt)
                S[mtg][nt] = mfma16(aK[mtg], bQ[nt], (mtg == 2) ? ci : z);
        }
        // ---- softmax over g (rows): per-lane partial + xor16/32 ----
        float inv[3];
#pragma unroll
        for (int nt = 0; nt < 3; ++nt){
            float t = 0.f;
#pragma unroll
            for (int mtg = 0; mtg < 3; ++mtg)
#pragma unroll
            for (int reg = 0; reg < 4; ++reg){
                S[mtg][nt][reg] = __expf(S[mtg][nt][reg]);
                t += S[mtg][nt][reg];
            }
            t += __shfl_xor(t, 16, 64);
            t += __shfl_xor(t, 32, 64);
            inv[nt] = 1.0f / t;
        }
        // ---- P^T -> pBuf (overlays kBuf+qBuf; reads already done) ----
#pragma unroll
        for (int mtg = 0; mtg < 3; ++mtg)
#pragma unroll
        for (int nt = 0; nt < 3; ++nt){
            f32x4 p;
#pragma unroll
            for (int reg = 0; reg < 4; ++reg) p[reg] = S[mtg][nt][reg]*inv[nt];
            store4(pBuf + ((mtg>>1)*3 + nt)*512 + (mtg&1)*256 + A_off, p);
        }
        wave_sync();

        // ---- O^T = V^T x P^T (12 MFMAs) ----
        s16x8 aV[2][2], bP[2][3];
#pragma unroll
        for (int ks = 0; ks < 2; ++ks){
#pragma unroll
            for (int emt = 0; emt < 2; ++emt)
                aV[ks][emt] = *(const s16x8*)(vBuf + (ks*2+emt)*512 + lane*8);
#pragma unroll
            for (int nt = 0; nt < 3; ++nt)
                bP[ks][nt] = *(const s16x8*)(pBuf + (ks*3+nt)*512 + lane*8);
        }
        if (L < 2){
#pragma unroll
            for (int emt = 0; emt < 2; ++emt)
#pragma unroll
            for (int nt = 0; nt < 3; ++nt){
                f32x4 o = mfma16(aV[1][emt], bP[1][nt],
                         mfma16(aV[0][emt], bP[0][nt], z));
                float m = (nt < 2 || nl < 7) ? 1.f : 0.f;   // zero cols f>=39
#pragma unroll
                for (int reg = 0; reg < 4; ++reg)
                    o[reg] = fmaxf(o[reg] + R[emt][nt][reg], 0.f) * m;
                store4(eBuf + nt*512 + emt*256 + A_off, o);
            }
        } else {
            int st = r >> 4, sm = r & 15;
            u32 base = (u32)(st*39)*512u + (u32)(sm*8 + (h>>1)*128 + (h&1)*4);
#pragma unroll
            for (int emt = 0; emt < 2; ++emt)
#pragma unroll
            for (int nt = 0; nt < 3; ++nt){
                f32x4 o = mfma16(aV[1][emt], bP[1][nt],
                         mfma16(aV[0][emt], bP[0][nt], z));
#pragma unroll
                for (int reg = 0; reg < 4; ++reg)
                    o[reg] = fmaxf(o[reg] + R[emt][nt][reg], 0.f);
                int f = nt*16 + nl;
                if (f < NF)
                    *(uint2*)(ws + base + (u32)f*512u + emt*256) =
                        make_uint2(pk2(o[0], o[1]), pk2(o[2], o[3]));
            }
        }
        wave_sync();
    }
}

// ================= K2: MLP, 1 sample-tile per block, nt-split =================
__global__ void __launch_bounds__(256, 4) mlp_kernel(
    const float* __restrict__ b1, const float* __restrict__ b2,
    const float* __restrict__ b3, const float* __restrict__ w4,
    const float* __restrict__ b4, const u16* __restrict__ ws,
    float* __restrict__ out)
{
    __shared__ __align__(16) u16 h1t[2048];  // h1^T B-frag: 4 ks tiles
    __shared__ __align__(16) u16 h2t[1024];  // h2^T B-frag: 2 ks tiles
    __shared__ float part[32];
    const int tid = (int)threadIdx.x;
    const int w   = tid >> 6, lane = tid & 63;
    const int h   = lane >> 4, nl = lane & 15;
    const int st  = (int)blockIdx.x;
    const int A_off = nl*8 + (h>>1)*128 + (h&1)*4;

    const u16* w1b = ws + E3_U16 + 12288u;
    const u16* w2b = w1b + 159744u;
    const u16* w3b = w2b + 8192u;
    const f32x4 z = {0.f,0.f,0.f,0.f};

    // ---- GEMM1: h1^T = w1^T x e3^T ; wave w owns feat tiles {2w, 2w+1} ----
    f32x4 acc[2] = {z, z};
#pragma unroll 2
    for (int ks = 0; ks < 39; ++ks){
        s16x8 aE = *(const s16x8*)(ws + (u32)(st*39 + ks)*512u + lane*8);
#pragma unroll
        for (int t = 0; t < 2; ++t){
            s16x8 aW = *(const s16x8*)(w1b + (ks*8 + 2*w + t)*512 + lane*8);
            acc[t] = mfma16(aW, aE, acc[t]);
        }
    }
#pragma unroll
    for (int t = 0; t < 2; ++t){
        float4 bv = *(const float4*)(b1 + (2*w + t)*16 + h*4);
        f32x4 v;
        v[0] = fmaxf(acc[t][0] + bv.x, 0.f);
        v[1] = fmaxf(acc[t][1] + bv.y, 0.f);
        v[2] = fmaxf(acc[t][2] + bv.z, 0.f);
        v[3] = fmaxf(acc[t][3] + bv.w, 0.f);
        store4(h1t + w*512 + t*256 + A_off, v);
    }
    __syncthreads();

    // ---- GEMM2: h2^T = w2^T x h1^T ; wave w owns feat tile w ----
    {
        f32x4 a2 = z;
#pragma unroll
        for (int ks = 0; ks < 4; ++ks){
            s16x8 aW = *(const s16x8*)(w2b + (ks*4 + w)*512 + lane*8);
            s16x8 bH = *(const s16x8*)(h1t + ks*512 + lane*8);
            a2 = mfma16(aW, bH, a2);
        }
        float4 bv = *(const float4*)(b2 + w*16 + h*4);
        f32x4 v;
        v[0] = fmaxf(a2[0] + bv.x, 0.f);
        v[1] = fmaxf(a2[1] + bv.y, 0.f);
        v[2] = fmaxf(a2[2] + bv.z, 0.f);
        v[3] = fmaxf(a2[3] + bv.w, 0.f);
        store4(h2t + (w>>1)*512 + (w&1)*256 + A_off, v);
    }
    __syncthreads();

    // ---- GEMM3 (waves 0,1) + w4 dot partials ----
    if (w < 2){
        f32x4 a3 = z;
#pragma unroll
        for (int ks = 0; ks < 2; ++ks){
            s16x8 aW = *(const s16x8*)(w3b + (ks*2 + w)*512 + lane*8);
            s16x8 bH = *(const s16x8*)(h2t + ks*512 + lane*8);
            a3 = mfma16(aW, bH, a3);
        }
        float4 b3v = *(const float4*)(b3 + w*16 + h*4);
        float4 w4v = *(const float4*)(w4 + w*16 + h*4);
        float t = fmaxf(a3[0] + b3v.x, 0.f)*w4v.x
                + fmaxf(a3[1] + b3v.y, 0.f)*w4v.y
                + fmaxf(a3[2] + b3v.z, 0.f)*w4v.z
                + fmaxf(a3[3] + b3v.w, 0.f)*w4v.w;
        t += __shfl_xor(t, 16, 64);
        t += __shfl_xor(t, 32, 64);
        if (h == 0) part[w*16 + nl] = t;
    }
    __syncthreads();
    if (tid < 16){
        float zz = part[tid] + part[16 + tid] + b4[0];
        out[st*16 + tid] = 1.f/(1.f + __expf(-zz));
    }
}

extern "C" void kernel_launch(void* const* d_in, const int* in_sizes, int n_in,
                              void* d_out, int out_size, void* d_ws, size_t ws_size,
                              hipStream_t stream)
{
    (void)in_sizes; (void)n_in; (void)ws_size; (void)out_size;
    const int*   x   = (const int*)d_in[0];
    const float* emb = (const float*)d_in[1];
    u16* ws = (u16*)d_ws;

    swz_kernel<<<(NSWZ+255)/256, 256, 0, stream>>>(
        (const float*)d_in[2],  (const float*)d_in[3],  (const float*)d_in[4],  (const float*)d_in[5],
        (const float*)d_in[6],  (const float*)d_in[7],  (const float*)d_in[8],  (const float*)d_in[9],
        (const float*)d_in[10], (const float*)d_in[11], (const float*)d_in[12], (const float*)d_in[13],
        (const float*)d_in[14], (const float*)d_in[16], (const float*)d_in[18], ws);

    attn_kernel<<<NB/4, 256, 0, stream>>>(x, emb, ws);

    mlp_kernel<<<NB/16, 256, 0, stream>>>(
        (const float*)d_in[15], (const float*)d_in[17], (const float*)d_in[19],
        (const float*)d_in[20], (const float*)d_in[21], ws, (float*)d_out);
}

// Round 6
// 192.140 us; speedup vs baseline: 14.5471x; 1.0167x over previous
//
#include <hip/hip_runtime.h>
#include <math.h>

#define NF   39
#define NB   16384
#define NVOC 10000

typedef unsigned short u16;
typedef unsigned int   u32;
typedef float f32x4 __attribute__((ext_vector_type(4)));
typedef short s16x8 __attribute__((ext_vector_type(8)));

// ---- d_ws layout (u16 units) ----
// [0, E3_U16): E3 activations, A-fragment tiles: (st, ks=f) -> 512 u16
// [E3_U16 ...): weights as 512-u16 fragment tiles:
//   12 attn mats (q,k,v,r × 3 layers) × 2 tiles = 12288
//   W1: (ks*8+nt), ks<39, nt<8  = 159744      W2: (ks*4+nt), ks<4, nt<4 = 8192
//   W3: (ks*2+nt), ks<2, nt<2   = 2048
#define E3_U16   20447232u
#define NSWZ     182272

__device__ __forceinline__ u32 bfadj(float x){
    u32 u = __float_as_uint(x);
    return u + 0x7fffu + ((u >> 16) & 1u);
}
// pack two fp32 -> two RNE bf16 in one u32 (low = a, high = b)
__device__ __forceinline__ u32 pk2(float a, float b){
#if __has_builtin(__builtin_amdgcn_cvt_pk_bf16_f32)
    auto t = __builtin_amdgcn_cvt_pk_bf16_f32(a, b);
    u32 r; __builtin_memcpy(&r, &t, 4); return r;
#else
    return __builtin_amdgcn_perm(bfadj(a), bfadj(b), 0x03020706u);
#endif
}
__device__ __forceinline__ u16 f2bf(float f){ return (u16)(bfadj(f) >> 16); }

__device__ __forceinline__ void wave_sync(){
    asm volatile("s_waitcnt lgkmcnt(0)" ::: "memory");
}
__device__ __forceinline__ f32x4 mfma16(s16x8 a, s16x8 b, f32x4 c){
    return __builtin_amdgcn_mfma_f32_16x16x32_bf16(a, b, c, 0, 0, 0);
}
// store 4 consecutive-k accumulator regs as packed bf16 (8 B)
__device__ __forceinline__ void store4(u16* p, f32x4 v){
    *(uint2*)p = make_uint2(pk2(v[0], v[1]), pk2(v[2], v[3]));
}

// ================= K0: weight pre-swizzle =================
__global__ void __launch_bounds__(256) swz_kernel(
    const float* __restrict__ wq0, const float* __restrict__ wk0,
    const float* __restrict__ wv0, const float* __restrict__ wr0,
    const float* __restrict__ wq1, const float* __restrict__ wk1,
    const float* __restrict__ wv1, const float* __restrict__ wr1,
    const float* __restrict__ wq2, const float* __restrict__ wk2,
    const float* __restrict__ wv2, const float* __restrict__ wr2,
    const float* __restrict__ w1, const float* __restrict__ w2,
    const float* __restrict__ w3, u16* __restrict__ ws)
{
    int gid = (int)blockIdx.x*256 + (int)threadIdx.x;
    if (gid >= NSWZ) return;
    int w    = gid & 511;
    int lane = w >> 3, j = w & 7;
    int n    = lane & 15, quad = lane >> 4;
    int kin  = quad*8 + j;
    float val;
    if (gid < 12288){
        int mat = gid >> 10;
        int nt  = (gid >> 9) & 1;
        const float* W;
        switch (mat){
            case 0: W = wq0; break; case 1: W = wk0; break;
            case 2: W = wv0; break; case 3: W = wr0; break;
            case 4: W = wq1; break; case 5: W = wk1; break;
            case 6: W = wv1; break; case 7: W = wr1; break;
            case 8: W = wq2; break; case 9: W = wk2; break;
            case 10: W = wv2; break; default: W = wr2; break;
        }
        int din = (mat < 4) ? 16 : 32;
        val = (kin < din) ? W[kin*32 + nt*16 + n] : 0.f;
    } else if (gid < 12288 + 159744){
        int tt = (gid - 12288) >> 9;
        int ks = tt >> 3, nt = tt & 7;
        val = w1[(ks*32 + kin)*128 + nt*16 + n];
    } else if (gid < 12288 + 159744 + 8192){
        int tt = (gid - (12288+159744)) >> 9;
        int ks = tt >> 2, nt = tt & 3;
        val = w2[(ks*32 + kin)*64 + nt*16 + n];
    } else {
        int tt = (gid - (12288+159744+8192)) >> 9;
        int ks = tt >> 1, nt = tt & 1;
        val = w3[(ks*32 + kin)*32 + nt*16 + n];
    }
    ws[E3_U16 + gid] = f2bf(val);
}

// ================= K1: fused attention, transpose-oriented =================
__global__ void __launch_bounds__(256, 3) attn_kernel(
    const int* __restrict__ x, const float* __restrict__ emb,
    u16* __restrict__ ws)
{
    __shared__ __align__(16) u16 lds[4*6656];
    const int tid  = (int)threadIdx.x;
    const int wid  = tid >> 6, lane = tid & 63;
    const int h    = lane >> 4, nl = lane & 15;
    const int r    = (int)blockIdx.x*4 + wid;

    u16* eBuf = lds + wid*6656;   // 1536: E  (A-frag of E == B-frag of E^T)
    u16* kBuf = eBuf + 1536;      // 1536: K  (B-frag of K^T)
    u16* qBuf = kBuf + 1536;      // 1536: Q^T B-frag
    u16* vBuf = qBuf + 1536;      // 2048: V B-frag (ks,emt)
    u16* pBuf = kBuf;             // 3072: P^T B-frag (ks*3+nt), overlays K+Q
    const u16* wmat = ws + E3_U16;
    const f32x4 z = {0.f, 0.f, 0.f, 0.f};
    const int A_off = nl*8 + (h>>1)*128 + (h&1)*4;

    // S^T C-init: pad rows g>=39 (only in mtg=2 tile: g = 32+h*4+reg)
    f32x4 ci;
#pragma unroll
    for (int reg = 0; reg < 4; ++reg)
        ci[reg] = (h*4 + reg >= 7) ? -1e30f : 0.f;

    // ---- embedding gather -> E A-frag ----
    if (lane < 48){
        int f = lane, mt = f >> 4, fl = f & 15;
        u16* row = eBuf + mt*512 + fl*8;
        if (f < NF){
            const float4* ep = (const float4*)(emb + ((size_t)(x[r*NF + f] + f*NVOC))*16);
            float4 e0 = ep[0], e1 = ep[1], e2 = ep[2], e3 = ep[3];
            *(uint4*)(row)       = make_uint4(pk2(e0.x,e0.y), pk2(e0.z,e0.w),
                                              pk2(e1.x,e1.y), pk2(e1.z,e1.w));
            *(uint4*)(row + 128) = make_uint4(pk2(e2.x,e2.y), pk2(e2.z,e2.w),
                                              pk2(e3.x,e3.y), pk2(e3.z,e3.w));
        } else {
            *(uint4*)(row)       = make_uint4(0,0,0,0);
            *(uint4*)(row + 128) = make_uint4(0,0,0,0);
        }
        *(uint4*)(row + 256) = make_uint4(0,0,0,0);
        *(uint4*)(row + 384) = make_uint4(0,0,0,0);
    }
    wave_sync();

#pragma unroll 1
    for (int L = 0; L < 3; ++L){
        const u16* wB = wmat + L*4096;
        s16x8 bE[3];
#pragma unroll
        for (int nt = 0; nt < 3; ++nt)
            bE[nt] = *(const s16x8*)(eBuf + nt*512 + lane*8);

        // ---- Q^T -> qBuf ----
        {
            s16x8 a0 = *(const s16x8*)(wB + lane*8);
            s16x8 a1 = *(const s16x8*)(wB + 512 + lane*8);
#pragma unroll
            for (int nt = 0; nt < 3; ++nt){
                store4(qBuf + nt*512       + A_off, mfma16(a0, bE[nt], z));
                store4(qBuf + nt*512 + 256 + A_off, mfma16(a1, bE[nt], z));
            }
        }
        // ---- K^T -> kBuf ----
        {
            s16x8 a0 = *(const s16x8*)(wB + 1024 + lane*8);
            s16x8 a1 = *(const s16x8*)(wB + 1536 + lane*8);
#pragma unroll
            for (int nt = 0; nt < 3; ++nt){
                store4(kBuf + nt*512       + A_off, mfma16(a0, bE[nt], z));
                store4(kBuf + nt*512 + 256 + A_off, mfma16(a1, bE[nt], z));
            }
        }
        // ---- V -> vBuf ----
        {
            s16x8 b0 = *(const s16x8*)(wB + 2048 + lane*8);
            s16x8 b1 = *(const s16x8*)(wB + 2560 + lane*8);
#pragma unroll
            for (int mtg = 0; mtg < 3; ++mtg){
                int toff = (mtg>>1)*1024 + (mtg&1)*256;
                store4(vBuf + toff       + A_off, mfma16(bE[mtg], b0, z));
                store4(vBuf + toff + 512 + A_off, mfma16(bE[mtg], b1, z));
            }
            *(uint2*)(vBuf + 2*512 + 256 + lane*4) = make_uint2(0,0);
            *(uint2*)(vBuf + 3*512 + 256 + lane*4) = make_uint2(0,0);
        }
        // ---- R^T in regs ----
        f32x4 R[2][3];
        {
            s16x8 a0 = *(const s16x8*)(wB + 3072 + lane*8);
            s16x8 a1 = *(const s16x8*)(wB + 3584 + lane*8);
#pragma unroll
            for (int nt = 0; nt < 3; ++nt){
                R[0][nt] = mfma16(a0, bE[nt], z);
                R[1][nt] = mfma16(a1, bE[nt], z);
            }
        }
        wave_sync();

        // ---- S^T = K x Q^T (9 MFMAs) ----
        f32x4 S[3][3];
        {
            s16x8 aK[3], bQ[3];
#pragma unroll
            for (int i = 0; i < 3; ++i){
                aK[i] = *(const s16x8*)(kBuf + i*512 + lane*8);
                bQ[i] = *(const s16x8*)(qBuf + i*512 + lane*8);
            }
#pragma unroll
            for (int mtg = 0; mtg < 3; ++mtg)
#pragma unroll
            for (int nt = 0; nt < 3; ++nt)
                S[mtg][nt] = mfma16(aK[mtg], bQ[nt], (mtg == 2) ? ci : z);
        }
        // ---- exp + rowsum; P stays UNNORMALIZED (inv folded into O epilogue) ----
        float inv[3];
#pragma unroll
        for (int nt = 0; nt < 3; ++nt){
            float t = 0.f;
#pragma unroll
            for (int mtg = 0; mtg < 3; ++mtg)
#pragma unroll
            for (int reg = 0; reg < 4; ++reg){
                S[mtg][nt][reg] = __expf(S[mtg][nt][reg]);
                t += S[mtg][nt][reg];
            }
            t += __shfl_xor(t, 16, 64);
            t += __shfl_xor(t, 32, 64);
            inv[nt] = 1.0f / t;
        }
        // ---- P^T (unnormalized) -> pBuf ----
#pragma unroll
        for (int mtg = 0; mtg < 3; ++mtg)
#pragma unroll
        for (int nt = 0; nt < 3; ++nt)
            store4(pBuf + ((mtg>>1)*3 + nt)*512 + (mtg&1)*256 + A_off, S[mtg][nt]);
        wave_sync();

        // ---- O^T = V^T x P^T (12 MFMAs) ----
        s16x8 aV[2][2], bP[2][3];
#pragma unroll
        for (int ks = 0; ks < 2; ++ks){
#pragma unroll
            for (int emt = 0; emt < 2; ++emt)
                aV[ks][emt] = *(const s16x8*)(vBuf + (ks*2+emt)*512 + lane*8);
#pragma unroll
            for (int nt = 0; nt < 3; ++nt)
                bP[ks][nt] = *(const s16x8*)(pBuf + (ks*3+nt)*512 + lane*8);
        }
        if (L < 2){
#pragma unroll
            for (int emt = 0; emt < 2; ++emt)
#pragma unroll
            for (int nt = 0; nt < 3; ++nt){
                f32x4 o = mfma16(aV[1][emt], bP[1][nt],
                         mfma16(aV[0][emt], bP[0][nt], z));
                float m = (nt < 2 || nl < 7) ? 1.f : 0.f;   // zero cols f>=39
#pragma unroll
                for (int reg = 0; reg < 4; ++reg)
                    o[reg] = fmaxf(fmaf(o[reg], inv[nt], R[emt][nt][reg]), 0.f) * m;
                store4(eBuf + nt*512 + emt*256 + A_off, o);
            }
        } else {
            int st = r >> 4, sm = r & 15;
            u32 base = (u32)(st*39)*512u + (u32)(sm*8 + (h>>1)*128 + (h&1)*4);
#pragma unroll
            for (int emt = 0; emt < 2; ++emt)
#pragma unroll
            for (int nt = 0; nt < 3; ++nt){
                f32x4 o = mfma16(aV[1][emt], bP[1][nt],
                         mfma16(aV[0][emt], bP[0][nt], z));
#pragma unroll
                for (int reg = 0; reg < 4; ++reg)
                    o[reg] = fmaxf(fmaf(o[reg], inv[nt], R[emt][nt][reg]), 0.f);
                int f = nt*16 + nl;
                if (f < NF)
                    *(uint2*)(ws + base + (u32)f*512u + emt*256) =
                        make_uint2(pk2(o[0], o[1]), pk2(o[2], o[3]));
            }
        }
        wave_sync();
    }
}

// ================= K2: MLP, 16 samples/block, K-split GEMM1 =================
__global__ void __launch_bounds__(256, 4) mlp_kernel(
    const float* __restrict__ b1, const float* __restrict__ b2,
    const float* __restrict__ b3, const float* __restrict__ w4,
    const float* __restrict__ b4, const u16* __restrict__ ws,
    float* __restrict__ out)
{
    __shared__ __align__(16) float red[8192];   // 4 partials x 8 nt-tiles x 256 f32
    __shared__ __align__(16) u16 h1t[2048];     // h1^T B-frag: 4 ks tiles
    __shared__ __align__(16) u16 h2t[1024];     // h2^T B-frag: 2 ks tiles
    __shared__ float part[32];
    const int tid = (int)threadIdx.x;
    const int w   = tid >> 6, lane = tid & 63;
    const int h   = lane >> 4, nl = lane & 15;
    const int st  = (int)blockIdx.x;
    const int A_off = nl*8 + (h>>1)*128 + (h&1)*4;

    const u16* w1b = ws + E3_U16 + 12288u;
    const u16* w2b = w1b + 159744u;
    const u16* w3b = w2b + 8192u;
    const f32x4 z = {0.f,0.f,0.f,0.f};

    // ---- GEMM1: h1^T = w1^T x e3^T, K split across 4 waves (stride-4) ----
    f32x4 acc[8];
#pragma unroll
    for (int nt = 0; nt < 8; ++nt) acc[nt] = z;
#pragma unroll 1
    for (int ks = w; ks < 39; ks += 4){
        s16x8 aE = *(const s16x8*)(ws + (u32)(st*39 + ks)*512u + lane*8);
#pragma unroll
        for (int nt = 0; nt < 8; ++nt){
            s16x8 aW = *(const s16x8*)(w1b + (ks*8 + nt)*512 + lane*8);
            acc[nt] = mfma16(aW, aE, acc[nt]);
        }
    }
#pragma unroll
    for (int nt = 0; nt < 8; ++nt)
        *(f32x4*)(red + (w*8 + nt)*256 + lane*4) = acc[nt];
    __syncthreads();

    // ---- reduce partials; wave w finalizes feature tiles {2w, 2w+1} ----
#pragma unroll
    for (int t = 0; t < 2; ++t){
        int ft = 2*w + t;
        f32x4 s = *(const f32x4*)(red + (0*8 + ft)*256 + lane*4);
#pragma unroll
        for (int p = 1; p < 4; ++p){
            f32x4 q = *(const f32x4*)(red + (p*8 + ft)*256 + lane*4);
#pragma unroll
            for (int reg = 0; reg < 4; ++reg) s[reg] += q[reg];
        }
        float4 bv = *(const float4*)(b1 + ft*16 + h*4);
        f32x4 v;
        v[0] = fmaxf(s[0] + bv.x, 0.f);
        v[1] = fmaxf(s[1] + bv.y, 0.f);
        v[2] = fmaxf(s[2] + bv.z, 0.f);
        v[3] = fmaxf(s[3] + bv.w, 0.f);
        store4(h1t + ft*256 + A_off, v);
    }
    __syncthreads();

    // ---- GEMM2: h2^T = w2^T x h1^T ; wave w owns feat tile w ----
    {
        f32x4 a2 = z;
#pragma unroll
        for (int ks = 0; ks < 4; ++ks){
            s16x8 aW = *(const s16x8*)(w2b + (ks*4 + w)*512 + lane*8);
            s16x8 bH = *(const s16x8*)(h1t + ks*512 + lane*8);
            a2 = mfma16(aW, bH, a2);
        }
        float4 bv = *(const float4*)(b2 + w*16 + h*4);
        f32x4 v;
        v[0] = fmaxf(a2[0] + bv.x, 0.f);
        v[1] = fmaxf(a2[1] + bv.y, 0.f);
        v[2] = fmaxf(a2[2] + bv.z, 0.f);
        v[3] = fmaxf(a2[3] + bv.w, 0.f);
        store4(h2t + (w>>1)*512 + (w&1)*256 + A_off, v);
    }
    __syncthreads();

    // ---- GEMM3 (waves 0,1) + w4 dot partials ----
    if (w < 2){
        f32x4 a3 = z;
#pragma unroll
        for (int ks = 0; ks < 2; ++ks){
            s16x8 aW = *(const s16x8*)(w3b + (ks*2 + w)*512 + lane*8);
            s16x8 bH = *(const s16x8*)(h2t + ks*512 + lane*8);
            a3 = mfma16(aW, bH, a3);
        }
        float4 b3v = *(const float4*)(b3 + w*16 + h*4);
        float4 w4v = *(const float4*)(w4 + w*16 + h*4);
        float t = fmaxf(a3[0] + b3v.x, 0.f)*w4v.x
                + fmaxf(a3[1] + b3v.y, 0.f)*w4v.y
                + fmaxf(a3[2] + b3v.z, 0.f)*w4v.z
                + fmaxf(a3[3] + b3v.w, 0.f)*w4v.w;
        t += __shfl_xor(t, 16, 64);
        t += __shfl_xor(t, 32, 64);
        if (h == 0) part[w*16 + nl] = t;
    }
    __syncthreads();
    if (tid < 16){
        float zz = part[tid] + part[16 + tid] + b4[0];
        out[st*16 + tid] = 1.f/(1.f + __expf(-zz));
    }
}

extern "C" void kernel_launch(void* const* d_in, const int* in_sizes, int n_in,
                              void* d_out, int out_size, void* d_ws, size_t ws_size,
                              hipStream_t stream)
{
    (void)in_sizes; (void)n_in; (void)ws_size; (void)out_size;
    const int*   x   = (const int*)d_in[0];
    const float* emb = (const float*)d_in[1];
    u16* ws = (u16*)d_ws;

    swz_kernel<<<(NSWZ+255)/256, 256, 0, stream>>>(
        (const float*)d_in[2],  (const float*)d_in[3],  (const float*)d_in[4],  (const float*)d_in[5],
        (const float*)d_in[6],  (const float*)d_in[7],  (const float*)d_in[8],  (const float*)d_in[9],
        (const float*)d_in[10], (const float*)d_in[11], (const float*)d_in[12], (const float*)d_in[13],
        (const float*)d_in[14], (const float*)d_in[16], (const float*)d_in[18], ws);

    attn_kernel<<<NB/4, 256, 0, stream>>>(x, emb, ws);

    mlp_kernel<<<NB/16, 256, 0, stream>>>(
        (const float*)d_in[15], (const float*)d_in[17], (const float*)d_in[19],
        (const float*)d_in[20], (const float*)d_in[21], ws, (float*)d_out);
}

// Round 7
// 189.629 us; speedup vs baseline: 14.7398x; 1.0132x over previous
//
#include <hip/hip_runtime.h>
#include <math.h>

#define NF   39
#define NB   16384
#define NVOC 10000

typedef unsigned short u16;
typedef unsigned int   u32;
typedef float f32x4 __attribute__((ext_vector_type(4)));
typedef short s16x8 __attribute__((ext_vector_type(8)));

// ---- d_ws layout (u16 units) ----
// [0, E3_U16): E3 activations, A-fragment tiles: (st, ks=f) -> 512 u16
// [E3_U16 ...): weights as 512-u16 fragment tiles:
//   12 attn mats (q,k,v,r × 3 layers) × 2 tiles = 12288   (wq pre-scaled by log2e)
//   W1: (ks*8+nt), ks<39, nt<8  = 159744      W2: (ks*4+nt), ks<4, nt<4 = 8192
//   W3: (ks*2+nt), ks<2, nt<2   = 2048
#define E3_U16   20447232u
#define NSWZ     182272

__device__ __forceinline__ u32 bfadj(float x){
    u32 u = __float_as_uint(x);
    return u + 0x7fffu + ((u >> 16) & 1u);
}
__device__ __forceinline__ u32 pk2(float a, float b){
#if __has_builtin(__builtin_amdgcn_cvt_pk_bf16_f32)
    auto t = __builtin_amdgcn_cvt_pk_bf16_f32(a, b);
    u32 r; __builtin_memcpy(&r, &t, 4); return r;
#else
    return __builtin_amdgcn_perm(bfadj(a), bfadj(b), 0x03020706u);
#endif
}
__device__ __forceinline__ u16 f2bf(float f){ return (u16)(bfadj(f) >> 16); }

__device__ __forceinline__ float fexp2(float x){
#if __has_builtin(__builtin_amdgcn_exp2f)
    return __builtin_amdgcn_exp2f(x);
#else
    return exp2f(x);
#endif
}
__device__ __forceinline__ float frcp(float x){
#if __has_builtin(__builtin_amdgcn_rcpf)
    return __builtin_amdgcn_rcpf(x);
#else
    return 1.f / x;
#endif
}

__device__ __forceinline__ void wave_sync(){
    asm volatile("s_waitcnt lgkmcnt(0)" ::: "memory");
}
__device__ __forceinline__ f32x4 mfma16(s16x8 a, s16x8 b, f32x4 c){
    return __builtin_amdgcn_mfma_f32_16x16x32_bf16(a, b, c, 0, 0, 0);
}
__device__ __forceinline__ void store4(u16* p, f32x4 v){
    *(uint2*)p = make_uint2(pk2(v[0], v[1]), pk2(v[2], v[3]));
}

// ================= K0: weight pre-swizzle =================
__global__ void __launch_bounds__(256) swz_kernel(
    const float* __restrict__ wq0, const float* __restrict__ wk0,
    const float* __restrict__ wv0, const float* __restrict__ wr0,
    const float* __restrict__ wq1, const float* __restrict__ wk1,
    const float* __restrict__ wv1, const float* __restrict__ wr1,
    const float* __restrict__ wq2, const float* __restrict__ wk2,
    const float* __restrict__ wv2, const float* __restrict__ wr2,
    const float* __restrict__ w1, const float* __restrict__ w2,
    const float* __restrict__ w3, u16* __restrict__ ws)
{
    int gid = (int)blockIdx.x*256 + (int)threadIdx.x;
    if (gid >= NSWZ) return;
    int w    = gid & 511;
    int lane = w >> 3, j = w & 7;
    int n    = lane & 15, quad = lane >> 4;
    int kin  = quad*8 + j;
    float val;
    if (gid < 12288){
        int mat = gid >> 10;
        int nt  = (gid >> 9) & 1;
        const float* W;
        switch (mat){
            case 0: W = wq0; break; case 1: W = wk0; break;
            case 2: W = wv0; break; case 3: W = wr0; break;
            case 4: W = wq1; break; case 5: W = wk1; break;
            case 6: W = wv1; break; case 7: W = wr1; break;
            case 8: W = wq2; break; case 9: W = wk2; break;
            case 10: W = wv2; break; default: W = wr2; break;
        }
        int din = (mat < 4) ? 16 : 32;
        val = (kin < din) ? W[kin*32 + nt*16 + n] : 0.f;
        if ((mat & 3) == 0) val *= 1.44269504f;   // wq: fold log2e -> softmax uses exp2
    } else if (gid < 12288 + 159744){
        int tt = (gid - 12288) >> 9;
        int ks = tt >> 3, nt = tt & 7;
        val = w1[(ks*32 + kin)*128 + nt*16 + n];
    } else if (gid < 12288 + 159744 + 8192){
        int tt = (gid - (12288+159744)) >> 9;
        int ks = tt >> 2, nt = tt & 3;
        val = w2[(ks*32 + kin)*64 + nt*16 + n];
    } else {
        int tt = (gid - (12288+159744+8192)) >> 9;
        int ks = tt >> 1, nt = tt & 1;
        val = w3[(ks*32 + kin)*32 + nt*16 + n];
    }
    ws[E3_U16 + gid] = f2bf(val);
}

// ================= K1: fused attention, transpose-oriented =================
// Per-wave LDS 5120 u16: vBuf(2048, E aliases tiles 0-2) | kBuf(1536) | qBuf(1536)
// pBuf(3072) overlays kBuf+qBuf. E consumed into regs at layer start; lgkmcnt
// fence before V writes clobber the region.
__global__ void __launch_bounds__(256, 4) attn_kernel(
    const int* __restrict__ x, const float* __restrict__ emb,
    u16* __restrict__ ws)
{
    __shared__ __align__(16) u16 lds[4*5120];
    const int tid  = (int)threadIdx.x;
    const int wid  = tid >> 6, lane = tid & 63;
    const int h    = lane >> 4, nl = lane & 15;
    const int r    = (int)blockIdx.x*4 + wid;

    u16* vBuf = lds + wid*5120;   // 2048: V B-frag (ks*2+emt); tiles 0-2 alias E
    u16* eBuf = vBuf;             // 1536: E A-frag (B-frag of E^T)
    u16* kBuf = vBuf + 2048;      // 1536: K (B-frag of K^T)
    u16* qBuf = kBuf + 1536;      // 1536: Q^T B-frag
    u16* pBuf = kBuf;             // 3072: P^T B-frag (ks*3+nt) overlays K+Q
    const u16* wmat = ws + E3_U16;
    const f32x4 z = {0.f, 0.f, 0.f, 0.f};
    const int A_off = nl*8 + (h>>1)*128 + (h&1)*4;

    // S^T C-init: pad rows g>=39 (mtg=2 tile: g = 32+h*4+reg)
    f32x4 ci;
#pragma unroll
    for (int reg = 0; reg < 4; ++reg)
        ci[reg] = (h*4 + reg >= 7) ? -1e30f : 0.f;

    // ---- embedding gather -> E A-frag ----
    if (lane < 48){
        int f = lane, mt = f >> 4, fl = f & 15;
        u16* row = eBuf + mt*512 + fl*8;
        if (f < NF){
            const float4* ep = (const float4*)(emb + ((size_t)(x[r*NF + f] + f*NVOC))*16);
            float4 e0 = ep[0], e1 = ep[1], e2 = ep[2], e3 = ep[3];
            *(uint4*)(row)       = make_uint4(pk2(e0.x,e0.y), pk2(e0.z,e0.w),
                                              pk2(e1.x,e1.y), pk2(e1.z,e1.w));
            *(uint4*)(row + 128) = make_uint4(pk2(e2.x,e2.y), pk2(e2.z,e2.w),
                                              pk2(e3.x,e3.y), pk2(e3.z,e3.w));
        } else {
            *(uint4*)(row)       = make_uint4(0,0,0,0);
            *(uint4*)(row + 128) = make_uint4(0,0,0,0);
        }
        *(uint4*)(row + 256) = make_uint4(0,0,0,0);
        *(uint4*)(row + 384) = make_uint4(0,0,0,0);
    }
    wave_sync();

#pragma unroll 1
    for (int L = 0; L < 3; ++L){
        const u16* wB = wmat + L*4096;
        s16x8 bE[3];
#pragma unroll
        for (int nt = 0; nt < 3; ++nt)
            bE[nt] = *(const s16x8*)(eBuf + nt*512 + lane*8);
        wave_sync();   // E fully in regs before V writes clobber the region

        // ---- Q^T -> qBuf ----
        {
            s16x8 a0 = *(const s16x8*)(wB + lane*8);
            s16x8 a1 = *(const s16x8*)(wB + 512 + lane*8);
#pragma unroll
            for (int nt = 0; nt < 3; ++nt){
                store4(qBuf + nt*512       + A_off, mfma16(a0, bE[nt], z));
                store4(qBuf + nt*512 + 256 + A_off, mfma16(a1, bE[nt], z));
            }
        }
        // ---- K^T -> kBuf ----
        {
            s16x8 a0 = *(const s16x8*)(wB + 1024 + lane*8);
            s16x8 a1 = *(const s16x8*)(wB + 1536 + lane*8);
#pragma unroll
            for (int nt = 0; nt < 3; ++nt){
                store4(kBuf + nt*512       + A_off, mfma16(a0, bE[nt], z));
                store4(kBuf + nt*512 + 256 + A_off, mfma16(a1, bE[nt], z));
            }
        }
        // ---- V -> vBuf (clobbers E region; E already in bE regs) ----
        {
            s16x8 b0 = *(const s16x8*)(wB + 2048 + lane*8);
            s16x8 b1 = *(const s16x8*)(wB + 2560 + lane*8);
#pragma unroll
            for (int mtg = 0; mtg < 3; ++mtg){
                int toff = (mtg>>1)*1024 + (mtg&1)*256;
                store4(vBuf + toff       + A_off, mfma16(bE[mtg], b0, z));
                store4(vBuf + toff + 512 + A_off, mfma16(bE[mtg], b1, z));
            }
            // zero V pad rows g=48..63 (ks=1 tiles, k-local 16..31)
            *(uint2*)(vBuf + 2*512 + 256 + lane*4) = make_uint2(0,0);
            *(uint2*)(vBuf + 3*512 + 256 + lane*4) = make_uint2(0,0);
        }
        // ---- R^T in regs (C layout of O^T) ----
        f32x4 R[2][3];
        {
            s16x8 a0 = *(const s16x8*)(wB + 3072 + lane*8);
            s16x8 a1 = *(const s16x8*)(wB + 3584 + lane*8);
#pragma unroll
            for (int nt = 0; nt < 3; ++nt){
                R[0][nt] = mfma16(a0, bE[nt], z);
                R[1][nt] = mfma16(a1, bE[nt], z);
            }
        }
        wave_sync();

        // ---- S^T = K x Q^T (9 MFMAs); logits already in log2 domain ----
        f32x4 S[3][3];
        {
            s16x8 aK[3], bQ[3];
#pragma unroll
            for (int i = 0; i < 3; ++i){
                aK[i] = *(const s16x8*)(kBuf + i*512 + lane*8);
                bQ[i] = *(const s16x8*)(qBuf + i*512 + lane*8);
            }
#pragma unroll
            for (int mtg = 0; mtg < 3; ++mtg)
#pragma unroll
            for (int nt = 0; nt < 3; ++nt)
                S[mtg][nt] = mfma16(aK[mtg], bQ[nt], (mtg == 2) ? ci : z);
        }
        // ---- exp2 + rowsum -> normalized P ----
        float inv[3];
#pragma unroll
        for (int nt = 0; nt < 3; ++nt){
            float t = 0.f;
#pragma unroll
            for (int mtg = 0; mtg < 3; ++mtg)
#pragma unroll
            for (int reg = 0; reg < 4; ++reg){
                S[mtg][nt][reg] = fexp2(S[mtg][nt][reg]);
                t += S[mtg][nt][reg];
            }
            t += __shfl_xor(t, 16, 64);
            t += __shfl_xor(t, 32, 64);
            inv[nt] = frcp(t);
        }
#pragma unroll
        for (int mtg = 0; mtg < 3; ++mtg)
#pragma unroll
        for (int nt = 0; nt < 3; ++nt){
            f32x4 p;
#pragma unroll
            for (int reg = 0; reg < 4; ++reg) p[reg] = S[mtg][nt][reg]*inv[nt];
            store4(pBuf + ((mtg>>1)*3 + nt)*512 + (mtg&1)*256 + A_off, p);
        }
        wave_sync();

        // ---- O^T = V^T x P^T (12 MFMAs), C-init = R ----
        s16x8 aV[2][2], bP[2][3];
#pragma unroll
        for (int ks = 0; ks < 2; ++ks){
#pragma unroll
            for (int emt = 0; emt < 2; ++emt)
                aV[ks][emt] = *(const s16x8*)(vBuf + (ks*2+emt)*512 + lane*8);
#pragma unroll
            for (int nt = 0; nt < 3; ++nt)
                bP[ks][nt] = *(const s16x8*)(pBuf + (ks*3+nt)*512 + lane*8);
        }
        wave_sync();   // all V/P reads in regs before epilogue overwrites E region
        if (L < 2){
#pragma unroll
            for (int emt = 0; emt < 2; ++emt)
#pragma unroll
            for (int nt = 0; nt < 3; ++nt){
                f32x4 o = mfma16(aV[1][emt], bP[1][nt],
                         mfma16(aV[0][emt], bP[0][nt], R[emt][nt]));
                float m = (nt < 2 || nl < 7) ? 1.f : 0.f;   // zero cols f>=39
#pragma unroll
                for (int reg = 0; reg < 4; ++reg)
                    o[reg] = fmaxf(o[reg], 0.f) * m;
                store4(eBuf + nt*512 + emt*256 + A_off, o);
            }
        } else {
            int st = r >> 4, sm = r & 15;
            u32 base = (u32)(st*39)*512u + (u32)(sm*8 + (h>>1)*128 + (h&1)*4);
#pragma unroll
            for (int emt = 0; emt < 2; ++emt)
#pragma unroll
            for (int nt = 0; nt < 3; ++nt){
                f32x4 o = mfma16(aV[1][emt], bP[1][nt],
                         mfma16(aV[0][emt], bP[0][nt], R[emt][nt]));
#pragma unroll
                for (int reg = 0; reg < 4; ++reg)
                    o[reg] = fmaxf(o[reg], 0.f);
                int f = nt*16 + nl;
                if (f < NF)
                    *(uint2*)(ws + base + (u32)f*512u + emt*256) =
                        make_uint2(pk2(o[0], o[1]), pk2(o[2], o[3]));
            }
        }
        wave_sync();
    }
}

// ================= K2: MLP, 16 samples/block, K-split GEMM1 =================
__global__ void __launch_bounds__(256, 4) mlp_kernel(
    const float* __restrict__ b1, const float* __restrict__ b2,
    const float* __restrict__ b3, const float* __restrict__ w4,
    const float* __restrict__ b4, const u16* __restrict__ ws,
    float* __restrict__ out)
{
    __shared__ __align__(16) float red[8192];
    __shared__ __align__(16) u16 h1t[2048];
    __shared__ __align__(16) u16 h2t[1024];
    __shared__ float part[32];
    const int tid = (int)threadIdx.x;
    const int w   = tid >> 6, lane = tid & 63;
    const int h   = lane >> 4, nl = lane & 15;
    const int st  = (int)blockIdx.x;
    const int A_off = nl*8 + (h>>1)*128 + (h&1)*4;

    const u16* w1b = ws + E3_U16 + 12288u;
    const u16* w2b = w1b + 159744u;
    const u16* w3b = w2b + 8192u;
    const f32x4 z = {0.f,0.f,0.f,0.f};

    // ---- GEMM1: h1^T = w1^T x e3^T, K split across 4 waves ----
    f32x4 acc[8];
#pragma unroll
    for (int nt = 0; nt < 8; ++nt) acc[nt] = z;
#pragma unroll 1
    for (int ks = w; ks < 39; ks += 4){
        s16x8 aE = *(const s16x8*)(ws + (u32)(st*39 + ks)*512u + lane*8);
#pragma unroll
        for (int nt = 0; nt < 8; ++nt){
            s16x8 aW = *(const s16x8*)(w1b + (ks*8 + nt)*512 + lane*8);
            acc[nt] = mfma16(aW, aE, acc[nt]);
        }
    }
#pragma unroll
    for (int nt = 0; nt < 8; ++nt)
        *(f32x4*)(red + (w*8 + nt)*256 + lane*4) = acc[nt];
    __syncthreads();

#pragma unroll
    for (int t = 0; t < 2; ++t){
        int ft = 2*w + t;
        f32x4 s = *(const f32x4*)(red + (0*8 + ft)*256 + lane*4);
#pragma unroll
        for (int p = 1; p < 4; ++p){
            f32x4 q = *(const f32x4*)(red + (p*8 + ft)*256 + lane*4);
#pragma unroll
            for (int reg = 0; reg < 4; ++reg) s[reg] += q[reg];
        }
        float4 bv = *(const float4*)(b1 + ft*16 + h*4);
        f32x4 v;
        v[0] = fmaxf(s[0] + bv.x, 0.f);
        v[1] = fmaxf(s[1] + bv.y, 0.f);
        v[2] = fmaxf(s[2] + bv.z, 0.f);
        v[3] = fmaxf(s[3] + bv.w, 0.f);
        store4(h1t + ft*256 + A_off, v);
    }
    __syncthreads();

    // ---- GEMM2: h2^T = w2^T x h1^T ----
    {
        f32x4 a2 = z;
#pragma unroll
        for (int ks = 0; ks < 4; ++ks){
            s16x8 aW = *(const s16x8*)(w2b + (ks*4 + w)*512 + lane*8);
            s16x8 bH = *(const s16x8*)(h1t + ks*512 + lane*8);
            a2 = mfma16(aW, bH, a2);
        }
        float4 bv = *(const float4*)(b2 + w*16 + h*4);
        f32x4 v;
        v[0] = fmaxf(a2[0] + bv.x, 0.f);
        v[1] = fmaxf(a2[1] + bv.y, 0.f);
        v[2] = fmaxf(a2[2] + bv.z, 0.f);
        v[3] = fmaxf(a2[3] + bv.w, 0.f);
        store4(h2t + (w>>1)*512 + (w&1)*256 + A_off, v);
    }
    __syncthreads();

    // ---- GEMM3 (waves 0,1) + w4 dot ----
    if (w < 2){
        f32x4 a3 = z;
#pragma unroll
        for (int ks = 0; ks < 2; ++ks){
            s16x8 aW = *(const s16x8*)(w3b + (ks*2 + w)*512 + lane*8);
            s16x8 bH = *(const s16x8*)(h2t + ks*512 + lane*8);
            a3 = mfma16(aW, bH, a3);
        }
        float4 b3v = *(const float4*)(b3 + w*16 + h*4);
        float4 w4v = *(const float4*)(w4 + w*16 + h*4);
        float t = fmaxf(a3[0] + b3v.x, 0.f)*w4v.x
                + fmaxf(a3[1] + b3v.y, 0.f)*w4v.y
                + fmaxf(a3[2] + b3v.z, 0.f)*w4v.z
                + fmaxf(a3[3] + b3v.w, 0.f)*w4v.w;
        t += __shfl_xor(t, 16, 64);
        t += __shfl_xor(t, 32, 64);
        if (h == 0) part[w*16 + nl] = t;
    }
    __syncthreads();
    if (tid < 16){
        float zz = part[tid] + part[16 + tid] + b4[0];
        out[st*16 + tid] = 1.f/(1.f + __expf(-zz));
    }
}

extern "C" void kernel_launch(void* const* d_in, const int* in_sizes, int n_in,
                              void* d_out, int out_size, void* d_ws, size_t ws_size,
                              hipStream_t stream)
{
    (void)in_sizes; (void)n_in; (void)ws_size; (void)out_size;
    const int*   x   = (const int*)d_in[0];
    const float* emb = (const float*)d_in[1];
    u16* ws = (u16*)d_ws;

    swz_kernel<<<(NSWZ+255)/256, 256, 0, stream>>>(
        (const float*)d_in[2],  (const float*)d_in[3],  (const float*)d_in[4],  (const float*)d_in[5],
        (const float*)d_in[6],  (const float*)d_in[7],  (const float*)d_in[8],  (const float*)d_in[9],
        (const float*)d_in[10], (const float*)d_in[11], (const float*)d_in[12], (const float*)d_in[13],
        (const float*)d_in[14], (const float*)d_in[16], (const float*)d_in[18], ws);

    attn_kernel<<<NB/4, 256, 0, stream>>>(x, emb, ws);

    mlp_kernel<<<NB/16, 256, 0, stream>>>(
        (const float*)d_in[15], (const float*)d_in[17], (const float*)d_in[19],
        (const float*)d_in[20], (const float*)d_in[21], ws, (float*)d_out);
}